// Round 12
// baseline (194.377 us; speedup 1.0000x reference)
//
#include <hip/hip_runtime.h>

// SKA: per-pixel dynamic depthwise 5x5 conv
// x: [B=8, C=256, H=64, W=64] f32
// w: [B=8, G=8, K2=25, H=64, W=64] f32
// out[b,c,h,w] = sum_k x[b,c,h+k/5-2,w+k%5-2] * w[b,g,k,h,w], g = c/32
//
// Design P4 (round 19): P2 skeleton + window-grid-aligned LDS -> b128 reads.
// Round-18 post-mortem: P3 (all reads up front) flat vs P2/P2b => request-
// shape axis exhausted. Cycle audit of P2 per CU: HBM ~15us, VALU 2.7us/SIMD,
// DS ~9.6us (80 ds_read_b64/thread-chunk: window starts at col wcol-2, 8B-
// not-16B-aligned in a data-aligned layout). DS tail is the last big
// unattacked pipe-term.
// Change (single axis: DS instruction count):
//  - LDS layout word(c,r,wincol)=c*1360+r*68+wincol, wincol=datacol+2.
//    Read window for quad j starts at wincol=4j -> 16B-aligned -> 2x
//    ds_read_b128 per row (40 vs 80 reads/chunk; ~12cyc vs 2x8cyc =>
//    DS 9.6 -> ~6.8us). Wave-b128's 8-addr/bank is the inherent floor
//    (round-3 lesson), not a penalty to fix.
//  - Staging writes the WINDOW grid: 17 aligned b128 quads/row (6
//    slots/thread, was 10 b64). Each quad built from two 8B-aligned float2
//    global loads (lo=cols 4q-2..4q-1, hi=4q..4q+1), clamped addrs,
//    pair-masked (q=0 lo / q=16 hi / OOB row -> exact 0.0 = jnp.pad).
//    Guard/pad zero pass deleted (every word written explicitly).
// Keep (frozen, P2/P2b-verified): 2-deep chunk prefetch, wk VGPR-resident
// (raw, loaded once), no-drain lgkmcnt-only barriers, grid 512 = 2
// blocks/CU, halves in slow blockIdx bits (XCD w-sharing), 4-chunk full
// unroll, FMA order unchanged (absmax must stay 0.0).
// Tripwires: VGPR 190-215 (256 => spill; WRITE_SIZE must stay 32768KB);
// LDS 43.5KB. Decision rule: flat (harness >=103) => all pipe terms
// falsified individually => declare structural plateau next round.

#define B_ 8
#define C_ 256
#define G_ 8
#define CG_ 32
#define H_ 64
#define W_ 64
#define K2_ 25
#define HW_ (H_ * W_)
#define NCH 4               // channels per chunk
#define NCHUNK 4            // chunks per block (half group = 16 channels)
#define NROWS 20            // 16-row band + 2 halo each side
#define PITCH 68            // words per window row = 17 aligned quads
#define CHW (NROWS * PITCH) // 1360 words per channel
#define BUFW (NCH * CHW)    // 5440 words = 21.76 KB per buffer
#define NSLOT 6             // staged quads per thread (1360 = 5*256 + 80)

// no-drain block barrier: commit my LDS writes, then raw s_barrier.
// (__syncthreads would add s_waitcnt vmcnt(0) = full VMEM drain.)
#define BARRIER_NODRAIN()                                \
  {                                                      \
    asm volatile("s_waitcnt lgkmcnt(0)" ::: "memory");   \
    __builtin_amdgcn_s_barrier();                        \
  }

// issue one chunk's staging loads: per slot, lo/hi float2 (8B-aligned,
// clamped in-bounds). Loads unconditional (addresses clamped) = branchless.
#define ISSUE(LO, HI, CH)                                    \
  {                                                          \
    const float* xn = xg + (size_t)(CH) * NCH * HW_;         \
    _Pragma("unroll") for (int it = 0; it < NSLOT; ++it) {   \
      LO[it] = *(const float2*)(xn + glo[it]);               \
      HI[it] = *(const float2*)(xn + ghi[it]);               \
    }                                                        \
  }

// build window-grid quads (masked) and b128-write them to buf at PB.
// slot 5 covers only idx 1280..1359 -> gated by tid<80.
#define STAGE(LO, HI, PB)                                    \
  {                                                          \
    _Pragma("unroll") for (int it = 0; it < NSLOT; ++it) {   \
      if (it < NSLOT - 1 || tid < 80) {                      \
        float4 v;                                            \
        v.x = mlo[it] ? LO[it].x : 0.0f;                     \
        v.y = mlo[it] ? LO[it].y : 0.0f;                     \
        v.z = mhi[it] ? HI[it].x : 0.0f;                     \
        v.w = mhi[it] ? HI[it].y : 0.0f;                     \
        *(float4*)&lds[(PB) + swo[it]] = v;                  \
      }                                                      \
    }                                                        \
  }

// compute NCH channel quads from buf at word offset PB into acc[][];
// both reads 16B-aligned b128 by construction.
#define COMPUTE(PB)                                                       \
  _Pragma("unroll") for (int c = 0; c < NCH; ++c) {                       \
    acc[c][0] = 0.f; acc[c][1] = 0.f; acc[c][2] = 0.f; acc[c][3] = 0.f;   \
  }                                                                       \
  _Pragma("unroll") for (int di = 0; di < 5; ++di) {                      \
    const int rbase = (PB) + (lr + di) * PITCH + wcol;                    \
    _Pragma("unroll") for (int c = 0; c < NCH; ++c) {                     \
      const int a0 = c * CHW + rbase;                                     \
      alignas(16) float xr[8];                                            \
      *(float4*)&xr[0] = *(const float4*)&lds[a0];                        \
      *(float4*)&xr[4] = *(const float4*)&lds[a0 + 4];                    \
      _Pragma("unroll") for (int dj = 0; dj < 5; ++dj) {                  \
        const float4 wv = wk[di * 5 + dj];                                \
        acc[c][0] = fmaf(xr[dj + 0], wv.x, acc[c][0]);                    \
        acc[c][1] = fmaf(xr[dj + 1], wv.y, acc[c][1]);                    \
        acc[c][2] = fmaf(xr[dj + 2], wv.z, acc[c][2]);                    \
        acc[c][3] = fmaf(xr[dj + 3], wv.w, acc[c][3]);                    \
      }                                                                   \
    }                                                                     \
  }

#define STORE(CH)                                                         \
  {                                                                       \
    float* ob = og + (size_t)(CH) * NCH * HW_;                            \
    *(float4*)(ob + (size_t)0 * HW_) = *(const float4*)acc[0];            \
    *(float4*)(ob + (size_t)1 * HW_) = *(const float4*)acc[1];            \
    *(float4*)(ob + (size_t)2 * HW_) = *(const float4*)acc[2];            \
    *(float4*)(ob + (size_t)3 * HW_) = *(const float4*)acc[3];            \
  }

__global__ __launch_bounds__(256, 2) void ska_kernel(
    const float* __restrict__ x, const float* __restrict__ w,
    float* __restrict__ out) {
  __shared__ __align__(16) float lds[2 * BUFW];  // 43.5 KB
  const int tid = threadIdx.x;
  const int lr = tid >> 4;   // output row within band (0..15)
  const int j = tid & 15;    // column quad (cols 4j..4j+3)
  const int wcol = j * 4;    // ALSO the window-grid word offset of the read

  // blockIdx = [half(1) | b(3) | g(3) | band(2)], 512 blocks = 2 per CU.
  const int blk = blockIdx.x;
  const int band = blk & 3;
  const int g = (blk >> 2) & 7;
  const int b = (blk >> 5) & 7;
  const int half = blk >> 8;  // 0/1: which 16 channels of the group

  const int h0 = band * 16;
  const int h = h0 + lr;

  // ---- staging slot precompute: slot idx = tid + 256*it over 1360 quads ----
  // quad (c, r, q): window row r (global row h0-2+r, clamped+masked),
  // window cols 4q..4q+3 = data cols 4q-2..4q+1.
  int glo[NSLOT], ghi[NSLOT], swo[NSLOT];
  bool mlo[NSLOT], mhi[NSLOT];
#pragma unroll
  for (int it = 0; it < NSLOT; ++it) {
    const int idx = min(tid + it * 256, NCH * NROWS * 17 - 1);
    const int c = idx / 340;          // magic-mul
    const int rem = idx - c * 340;
    const int r = rem / 17;           // window row 0..19
    const int q = rem - r * 17;       // window quad 0..16
    const int gr = h0 - 2 + r;        // global row, may be OOB
    const bool rowok = (unsigned)gr < (unsigned)H_;
    const int grc = min(max(gr, 0), H_ - 1);
    const int base = c * HW_ + grc * W_;
    glo[it] = base + max(4 * q - 2, 0);        // lo pair: data 4q-2,4q-1
    ghi[it] = base + min(4 * q, W_ - 2);       // hi pair: data 4q,4q+1
    mlo[it] = rowok && (q >= 1);
    mhi[it] = rowok && (q <= 15);
    swo[it] = c * CHW + r * PITCH + q * 4;     // 16B-aligned b128 target
  }

  const size_t chanbase = (size_t)(b * C_ + g * CG_ + half * 16) * HW_;
  const float* xg = x + chanbase;
  float* og = out + chanbase + (size_t)h * W_ + wcol;

  // ---- prologue: issue chunk 0 AND chunk 1 loads (2-deep from the start) ----
  float2 ALO[NSLOT], AHI[NSLOT];   // reg set A
  float2 BLO[NSLOT], BHI[NSLOT];   // reg set B
  ISSUE(ALO, AHI, 0)
  ISSUE(BLO, BHI, 1)

  // ---- load ALL 25 weight quads RAW, once (VGPR-resident all kernel) ----
  const float* wb =
      w + (size_t)(b * G_ + g) * K2_ * HW_ + (size_t)h * W_ + wcol;
  float4 wk[K2_];
#pragma unroll
  for (int k = 0; k < K2_; ++k)
    wk[k] = *(const float4*)(wb + (size_t)k * HW_);

  STAGE(ALO, AHI, 0)   // chunk 0 -> buf0 (waits only chunk-0 loads)
  BARRIER_NODRAIN()

  alignas(16) float acc[NCH][4];

  // ---- chunk 0: issue ch2 into A; compute buf0; stage chunk1 -> buf1 ----
  ISSUE(ALO, AHI, 2)
  COMPUTE(0)
  STAGE(BLO, BHI, BUFW)
  BARRIER_NODRAIN()
  STORE(0)

  // ---- chunk 1: issue ch3 into B; compute buf1; stage chunk2 -> buf0 ----
  ISSUE(BLO, BHI, 3)
  COMPUTE(BUFW)
  STAGE(ALO, AHI, 0)
  BARRIER_NODRAIN()
  STORE(1)

  // ---- chunk 2: compute buf0; stage chunk3 -> buf1 ----
  COMPUTE(0)
  STAGE(BLO, BHI, BUFW)
  BARRIER_NODRAIN()
  STORE(2)

  // ---- chunk 3: compute buf1; store ----
  COMPUTE(BUFW)
  STORE(3)
}

extern "C" void kernel_launch(void* const* d_in, const int* in_sizes, int n_in,
                              void* d_out, int out_size, void* d_ws,
                              size_t ws_size, hipStream_t stream) {
  const float* x = (const float*)d_in[0];
  const float* w = (const float*)d_in[1];
  float* out = (float*)d_out;
  // grid: 2 halves * 8 b * 8 g * 4 bands = 512 blocks of 256 threads
  ska_kernel<<<dim3(512), dim3(256), 0, stream>>>(x, w, out);
}

// Round 13
// 103.847 us; speedup vs baseline: 1.8718x; 1.8718x over previous
//
#include <hip/hip_runtime.h>

// SKA: per-pixel dynamic depthwise 5x5 conv
// x: [B=8, C=256, H=64, W=64] f32
// w: [B=8, G=8, K2=25, H=64, W=64] f32
// out[b,c,h,w] = sum_k x[b,c,h+k/5-2,w+k%5-2] * w[b,g,k,h,w], g = c/32
//
// Design P2x (round 20): EXACT round-8 P2 (best: 104.6 harness, ska
// ~29.6us) + ONE change: XCD co-location remap of blockIdx.
// Round-19 post-mortem: P4 spilled (VGPR=128 cap + 133MB scratch,
// WRITE_SIZE 169MB) — reverted. DS audit corrected: P2's DS term is
// ~2.7us/CU, not 9.6 — b128 windows were never the lever.
// Falsified axes so far: LDS pitch/conflicts, w-side masks, w-in-VGPR
// residency, barrier flavor, front-issue MLP, zero-LDS free-run, b128.
// P2 audit: FMA 2.7us + DS 2.7us + HBM floor 15.7us vs 29.6us measured
// => HBM duty ~53%; remaining structure-level lever = L2 locality.
// Change: blockIdx = [band(2)|half(1)|b(3)|g(3)] (was [half|b|g|band]).
// Old layout: adjacent bands (halo overlap = 4 of 20 staged rows, ~8MB
// of x) sat on DIFFERENT XCDs -> halo re-fetch missed L2. New layout:
// band stride 128 == 0 mod 8 and half stride 64 == 0 mod 8 => all 8
// blocks of one (b,g) [4 bands x 2 halves] share one XCD/L2: band halos
// and the w half-slice both become L2 hits. Consecutive blk = different
// g => 64 blocks/XCD, exactly balanced. Bijective, zero added work.
// Keep VERBATIM from P2: 2-deep chunk prefetch (rA/rB), w fully
// VGPR-resident (25 quads raw, loaded once), PITCH=66 b64 reads
// (4-addr/bank floor), staged-zero OOB rows (exact jnp.pad semantics),
// zeroed guards/pads, stores after barrier, __syncthreads barriers,
// __launch_bounds__(256,2), grid 512 = 2 blocks/CU, 4-chunk full unroll,
// FMA order unchanged (absmax must stay 0.0).
// Decision rule: <=103 => locality axis live, refine. Flat => declare
// practical plateau next round (occupancy capped at 2 waves/SIMD by
// VGPR-resident per-pixel weights => ~53% HBM duty is this structure's
// ceiling).

#define B_ 8
#define C_ 256
#define G_ 8
#define CG_ 32
#define H_ 64
#define W_ 64
#define K2_ 25
#define HW_ (H_ * W_)
#define NCH 4               // channels per chunk
#define NCHUNK 4            // chunks per block (half group = 16 channels)
#define NROWS 20            // 16-row band + 2 halo each side
#define PITCH 66            // 64 data + 2 pad words; stride == 2 mod 32 banks
#define CHSTRIDE 1322       // 2 guard words + 20*66
#define BUFW (NCH * CHSTRIDE)  // 5288 words = 21.2 KB per buffer

#define ISSUE(R0, R1, R2, R3, R4, CH)                    \
  {                                                      \
    const float* xn = xg + (size_t)(CH) * NCH * HW_;     \
    R0 = *(const float4*)(xn + soff[0]);                 \
    R1 = *(const float4*)(xn + soff[1]);                 \
    R2 = *(const float4*)(xn + soff[2]);                 \
    R3 = *(const float4*)(xn + soff[3]);                 \
    R4 = *(const float4*)(xn + soff[4]);                 \
  }

// OOB rows staged as exact 0 (= jnp.pad); cndmask consumes loads right at
// the ds_write, which is where the vmcnt wait belongs anyway.
#define STAGE(R0, R1, R2, R3, R4, PB)                                     \
  {                                                                       \
    const float4 z4 = make_float4(0.f, 0.f, 0.f, 0.f);                    \
    const float4 v0 = sok[0] ? R0 : z4;                                   \
    const float4 v1 = sok[1] ? R1 : z4;                                   \
    const float4 v2 = sok[2] ? R2 : z4;                                   \
    const float4 v3 = sok[3] ? R3 : z4;                                   \
    const float4 v4 = sok[4] ? R4 : z4;                                   \
    *(float2*)&lds[(PB) + swo[0]] = make_float2(v0.x, v0.y);              \
    *(float2*)&lds[(PB) + swo[0] + 2] = make_float2(v0.z, v0.w);          \
    *(float2*)&lds[(PB) + swo[1]] = make_float2(v1.x, v1.y);              \
    *(float2*)&lds[(PB) + swo[1] + 2] = make_float2(v1.z, v1.w);          \
    *(float2*)&lds[(PB) + swo[2]] = make_float2(v2.x, v2.y);              \
    *(float2*)&lds[(PB) + swo[2] + 2] = make_float2(v2.z, v2.w);          \
    *(float2*)&lds[(PB) + swo[3]] = make_float2(v3.x, v3.y);              \
    *(float2*)&lds[(PB) + swo[3] + 2] = make_float2(v3.z, v3.w);          \
    *(float2*)&lds[(PB) + swo[4]] = make_float2(v4.x, v4.y);              \
    *(float2*)&lds[(PB) + swo[4] + 2] = make_float2(v4.z, v4.w);          \
  }

// compute NCH channel quads from buf at word offset PB into acc[][]
#define COMPUTE(PB)                                                       \
  _Pragma("unroll") for (int c = 0; c < NCH; ++c) {                       \
    acc[c][0] = 0.f; acc[c][1] = 0.f; acc[c][2] = 0.f; acc[c][3] = 0.f;   \
  }                                                                       \
  _Pragma("unroll") for (int di = 0; di < 5; ++di) {                      \
    const int rbase = (PB) + (lr + di) * PITCH + wcol;                    \
    _Pragma("unroll") for (int c = 0; c < NCH; ++c) {                     \
      const int a0 = c * CHSTRIDE + rbase;                                \
      alignas(16) float xr[8];                                            \
      *(float2*)&xr[0] = *(const float2*)&lds[a0];                        \
      *(float2*)&xr[2] = *(const float2*)&lds[a0 + 2];                    \
      *(float2*)&xr[4] = *(const float2*)&lds[a0 + 4];                    \
      *(float2*)&xr[6] = *(const float2*)&lds[a0 + 6];                    \
      _Pragma("unroll") for (int dj = 0; dj < 5; ++dj) {                  \
        const float4 wv = wk[di * 5 + dj];                                \
        acc[c][0] = fmaf(xr[dj + 0], wv.x, acc[c][0]);                    \
        acc[c][1] = fmaf(xr[dj + 1], wv.y, acc[c][1]);                    \
        acc[c][2] = fmaf(xr[dj + 2], wv.z, acc[c][2]);                    \
        acc[c][3] = fmaf(xr[dj + 3], wv.w, acc[c][3]);                    \
      }                                                                   \
    }                                                                     \
  }

#define STORE(CH)                                                         \
  {                                                                       \
    float* ob = og + (size_t)(CH) * NCH * HW_;                            \
    *(float4*)(ob + (size_t)0 * HW_) = *(const float4*)acc[0];            \
    *(float4*)(ob + (size_t)1 * HW_) = *(const float4*)acc[1];            \
    *(float4*)(ob + (size_t)2 * HW_) = *(const float4*)acc[2];            \
    *(float4*)(ob + (size_t)3 * HW_) = *(const float4*)acc[3];            \
  }

__global__ __launch_bounds__(256, 2) void ska_kernel(
    const float* __restrict__ x, const float* __restrict__ w,
    float* __restrict__ out) {
  __shared__ __align__(16) float lds[2 * BUFW];  // 41.3 KB
  const int tid = threadIdx.x;
  const int lr = tid >> 4;   // output row within band (0..15)
  const int j = tid & 15;    // column quad (cols 4j..4j+3)
  const int wcol = j * 4;

  // blockIdx = [band(2) | half(1) | b(3) | g(3)], 512 blocks = 2 per CU.
  // band stride 128 == 0 mod 8, half stride 64 == 0 mod 8 => the 8 blocks
  // of one (b,g) (4 bands x 2 halves) share one XCD: x band-halos and the
  // w half-slice hit that XCD's L2. Consecutive blk = different g =>
  // demand spread evenly, 64 blocks per XCD.
  const int blk = blockIdx.x;
  const int g = blk & 7;
  const int b = (blk >> 3) & 7;
  const int half = (blk >> 6) & 1;
  const int band = blk >> 7;

  const int h0 = band * 16;
  const int h = h0 + lr;

  // ---- chunk-invariant staging slots: 5 per thread ----
  int soff[5];   // x word offset within chunk (c*HW + clamped_row*W + q*4)
  int swo[5];    // LDS word offset within buffer
  bool sok[5];   // row in bounds?
#pragma unroll
  for (int it = 0; it < 5; ++it) {
    const int i = tid + it * 256;
    const int c = i / 320;            // magic-mul
    const int rem = i - c * 320;
    const int rl = rem >> 4;          // window row 0..19
    const int q = rem & 15;           // column quad
    const int gr = h0 - 2 + rl;       // global row, may be OOB
    sok[it] = (unsigned)gr < (unsigned)H_;
    const int grc = min(max(gr, 0), H_ - 1);
    soff[it] = c * HW_ + grc * W_ + q * 4;
    swo[it] = c * CHSTRIDE + 2 + rl * PITCH + q * 4;  // 8B aligned
  }

  // ---- zero guards (2/ch) + row pads (2/row): 42 words x 4 ch, BOTH bufs ----
  if (tid < NCH * 42) {
    const int c = tid / 42;
    const int p = tid - c * 42;
    const int word =
        (p < 2) ? p : (2 + ((p - 2) >> 1) * PITCH + 64 + ((p - 2) & 1));
    lds[c * CHSTRIDE + word] = 0.0f;
    lds[BUFW + c * CHSTRIDE + word] = 0.0f;
  }

  const size_t chanbase = (size_t)(b * C_ + g * CG_ + half * 16) * HW_;
  const float* xg = x + chanbase;
  float* og = out + chanbase + (size_t)h * W_ + wcol;

  // ---- prologue: issue chunk 0 AND chunk 1 loads (2-deep from the start) ----
  float4 a0, a1, a2, a3, a4;   // reg set A
  float4 b0, b1, b2, b3, b4;   // reg set B
  ISSUE(a0, a1, a2, a3, a4, 0)
  ISSUE(b0, b1, b2, b3, b4, 1)

  // ---- load ALL 25 weight quads RAW, once (VGPR-resident all kernel) ----
  const float* wb =
      w + (size_t)(b * G_ + g) * K2_ * HW_ + (size_t)h * W_ + wcol;
  float4 wk[K2_];
#pragma unroll
  for (int k = 0; k < K2_; ++k)
    wk[k] = *(const float4*)(wb + (size_t)k * HW_);

  STAGE(a0, a1, a2, a3, a4, 0)   // chunk 0 -> buf0 (waits only chunk-0 loads)
  __syncthreads();

  alignas(16) float acc[NCH][4];

  // ---- chunk 0: issue ch2 into A; compute buf0; stage chunk1 -> buf1 ----
  ISSUE(a0, a1, a2, a3, a4, 2)
  COMPUTE(0)
  STAGE(b0, b1, b2, b3, b4, BUFW)
  __syncthreads();
  STORE(0)

  // ---- chunk 1: issue ch3 into B; compute buf1; stage chunk2 -> buf0 ----
  ISSUE(b0, b1, b2, b3, b4, 3)
  COMPUTE(BUFW)
  STAGE(a0, a1, a2, a3, a4, 0)
  __syncthreads();
  STORE(1)

  // ---- chunk 2: compute buf0; stage chunk3 -> buf1 ----
  COMPUTE(0)
  STAGE(b0, b1, b2, b3, b4, BUFW)
  __syncthreads();
  STORE(2)

  // ---- chunk 3: compute buf1; store ----
  COMPUTE(BUFW)
  STORE(3)
}

extern "C" void kernel_launch(void* const* d_in, const int* in_sizes, int n_in,
                              void* d_out, int out_size, void* d_ws,
                              size_t ws_size, hipStream_t stream) {
  const float* x = (const float*)d_in[0];
  const float* w = (const float*)d_in[1];
  float* out = (float*)d_out;
  // grid: 4 bands * 2 halves * 8 b * 8 g = 512 blocks of 256 threads
  ska_kernel<<<dim3(512), dim3(256), 0, stream>>>(x, w, out);
}